// Round 6
// baseline (607.072 us; speedup 1.0000x reference)
//
#include <hip/hip_runtime.h>
#include <stdint.h>

#define AS1 __attribute__((address_space(1)))
#define AS3 __attribute__((address_space(3)))

typedef unsigned short ushort_t;
typedef __attribute__((ext_vector_type(8))) short bf16x8;
typedef __attribute__((ext_vector_type(4))) float f32x4;

__device__ __forceinline__ ushort_t f2bf(float f) {
  union { float f; uint32_t u; } c; c.f = f;
  uint32_t u = c.u;
  return (ushort_t)((u + 0x7fffu + ((u >> 16) & 1u)) >> 16);  // RNE
}

// ---------------- prep kernels ----------------

__global__ __launch_bounds__(256) void k_cvt4(const float* __restrict__ in,
                                              ushort_t* __restrict__ out, int n4) {
  int i = blockIdx.x * blockDim.x + threadIdx.x;
  int stride = gridDim.x * blockDim.x;
  for (; i < n4; i += stride) {
    float4 v = ((const float4*)in)[i];
    ushort4 o;
    o.x = f2bf(v.x); o.y = f2bf(v.y); o.z = f2bf(v.z); o.w = f2bf(v.w);
    ((ushort4*)out)[i] = o;
  }
}

__global__ __launch_bounds__(256) void k_suminit(const float* __restrict__ init,
                                                 float* __restrict__ s) {
  int i = blockIdx.x * 256 + threadIdx.x;
  if (i < 1024) s[i] = init[i] + init[i + 1024] + init[i + 2048];
}

// all 6 weight transposes in one launch: W [K][N=1024] fp32 -> Wt [N][K] bf16
__global__ __launch_bounds__(256) void k_prep_w(
    const float* s0, const float* s1, const float* s2, const float* s3,
    const float* s4, const float* s5,
    ushort_t* d0, ushort_t* d1, ushort_t* d2, ushort_t* d3,
    ushort_t* d4, ushort_t* d5) {
  const float* S; ushort_t* D; int K = 1024;
  switch (blockIdx.z) {
    case 0: S = s0; D = d0; K = 512; break;
    case 1: S = s1; D = d1; break;
    case 2: S = s2; D = d2; break;
    case 3: S = s3; D = d3; break;
    case 4: S = s4; D = d4; break;
    default: S = s5; D = d5; break;
  }
  int k0 = blockIdx.y * 32;
  if (k0 >= K) return;
  __shared__ float tile[32][33];
  int tx = threadIdx.x & 31, ty = threadIdx.x >> 5;  // 32 x 8
  int n0 = blockIdx.x * 32;
  #pragma unroll
  for (int i = ty; i < 32; i += 8)
    tile[i][tx] = S[(size_t)(k0 + i) * 1024 + (n0 + tx)];
  __syncthreads();
  #pragma unroll
  for (int i = ty; i < 32; i += 8)
    D[(size_t)(n0 + i) * K + (k0 + tx)] = f2bf(tile[tx][i]);
}

// ---------------- GEMM: C[M,1024] = A[M,KT] * Bt[1024,KT]^T  (bf16 in, fp32 acc) ----------------
// EPI 0: C = bf16(relu(acc+bias))
// EPI 1: C = bf16(3*relu(acc+bias) + extra[col])
// EPI 2: C = bf16(3*relu(acc+bias))
// EPI 3: decoder fusion: part[slot][row] = sum_cols relu(acc+bias)*extra[col]  (no C write)

template <int KT, int EPI>
__global__ __launch_bounds__(256, 5)
void gemm_bt(const ushort_t* __restrict__ A, const ushort_t* __restrict__ Bt,
             const float* __restrict__ bias, const float* __restrict__ extra,
             ushort_t* __restrict__ C, float* __restrict__ part) {
  __shared__ char smem[32768];
  char* smA = smem;            // [128 rows][128 bytes] (BK=64 bf16), XOR-swizzled content
  char* smB = smem + 16384;    // same for Bt tile

  // XCD-aware swizzle: nwg = 2048, divisible by 8
  const int nwg = gridDim.x;
  const int cpx = nwg >> 3;
  int bid = blockIdx.x;
  int wg = (bid & 7) * cpx + (bid >> 3);
  const int mt = wg >> 3;  // 256 m-tiles
  const int nt = wg & 7;   // 8 n-tiles

  const int t = threadIdx.x;
  const int wave = t >> 6;
  const int lane = t & 63;
  const int wr = wave >> 1, wc = wave & 1;
  const int lrow = lane & 15;
  const int kq = lane >> 4;

  const char* Abase = (const char*)A + (size_t)mt * 128 * (KT * 2);
  const char* Bbase = (const char*)Bt + (size_t)nt * 128 * (KT * 2);

  // staging geometry: call i stages rows [i*32 .. i*32+31]; this thread's row:
  const int rbase = wave * 8 + (lane >> 3);
  // pre-swizzled global source column (16B units XORed with row&7)
  const int colOff = ((lane & 7) ^ (rbase & 7)) << 4;

  f32x4 acc[4][4];
  #pragma unroll
  for (int m = 0; m < 4; ++m)
    #pragma unroll
    for (int n = 0; n < 4; ++n)
      acc[m][n] = (f32x4){0.f, 0.f, 0.f, 0.f};

  constexpr int NKT = KT / 64;
  for (int kt = 0; kt < NKT; ++kt) {
    const size_t kb = (size_t)kt * 128;  // byte offset of K-tile in a row
    #pragma unroll
    for (int i = 0; i < 4; ++i) {
      int r = i * 32 + rbase;
      __builtin_amdgcn_global_load_lds(
          (const AS1 void*)(Abase + (size_t)r * (KT * 2) + kb + colOff),
          (AS3 void*)(smA + i * 4096 + wave * 1024), 16, 0, 0);
      __builtin_amdgcn_global_load_lds(
          (const AS1 void*)(Bbase + (size_t)r * (KT * 2) + kb + colOff),
          (AS3 void*)(smB + i * 4096 + wave * 1024), 16, 0, 0);
    }
    __syncthreads();
    #pragma unroll
    for (int ks = 0; ks < 2; ++ks) {
      bf16x8 af[4], bfv[4];
      #pragma unroll
      for (int m = 0; m < 4; ++m) {
        int r = wr * 64 + m * 16 + lrow;
        af[m] = *(const bf16x8*)(smA + r * 128 +
                                 ((ks * 64 + kq * 16) ^ ((r & 7) << 4)));
      }
      #pragma unroll
      for (int n = 0; n < 4; ++n) {
        int r = wc * 64 + n * 16 + lrow;
        bfv[n] = *(const bf16x8*)(smB + r * 128 +
                                  ((ks * 64 + kq * 16) ^ ((r & 7) << 4)));
      }
      #pragma unroll
      for (int m = 0; m < 4; ++m)
        #pragma unroll
        for (int n = 0; n < 4; ++n)
          acc[m][n] = __builtin_amdgcn_mfma_f32_16x16x32_bf16(af[m], bfv[n],
                                                              acc[m][n], 0, 0, 0);
    }
    __syncthreads();
  }

  // epilogue: C/D layout col = lane&15, row = (lane>>4)*4 + j
  const int row0 = mt * 128 + wr * 64;
  const int col0 = nt * 128 + wc * 64;
  if (EPI == 3) {
    float s[4][4];
    #pragma unroll
    for (int m = 0; m < 4; ++m)
      #pragma unroll
      for (int j = 0; j < 4; ++j) s[m][j] = 0.f;
    #pragma unroll
    for (int n = 0; n < 4; ++n) {
      int col = col0 + n * 16 + lrow;
      float bn = bias[col];
      float wn = extra[col];  // dec_w
      #pragma unroll
      for (int m = 0; m < 4; ++m)
        #pragma unroll
        for (int j = 0; j < 4; ++j) {
          float v = fmaxf(acc[m][n][j] + bn, 0.f);
          s[m][j] += v * wn;
        }
    }
    const int slot = nt * 2 + wc;
    #pragma unroll
    for (int m = 0; m < 4; ++m)
      #pragma unroll
      for (int j = 0; j < 4; ++j) {
        float v = s[m][j];
        v += __shfl_xor(v, 1);
        v += __shfl_xor(v, 2);
        v += __shfl_xor(v, 4);
        v += __shfl_xor(v, 8);
        if (lrow == 0)
          part[(size_t)slot * 32768 + (row0 + m * 16 + kq * 4 + j)] = v;
      }
  } else {
    float bn[4], en[4];
    #pragma unroll
    for (int n = 0; n < 4; ++n) {
      int col = col0 + n * 16 + lrow;
      bn[n] = bias[col];
      en[n] = (EPI == 1) ? extra[col] : 0.f;
    }
    // row-coherent store order: complete each 128B C line back-to-back
    #pragma unroll
    for (int m = 0; m < 4; ++m) {
      #pragma unroll
      for (int j = 0; j < 4; ++j) {
        int rb = row0 + m * 16 + kq * 4 + j;
        ushort_t* Crow = C + (size_t)rb * 1024 + col0 + lrow;
        #pragma unroll
        for (int n = 0; n < 4; ++n) {
          float v = acc[m][n][j] + bn[n];
          v = fmaxf(v, 0.f);
          if (EPI == 1) v = 3.f * v + en[n];
          else if (EPI == 2) v = 3.f * v;
          Crow[n * 16] = f2bf(v);
        }
      }
    }
  }
}

// ---------------- final decode reduce: out[r*3+{0,1,2}] = sum_s part[s][r] + dec_b ----------------

__global__ __launch_bounds__(256) void k_decfinal(const float* __restrict__ part,
                                                  const float* __restrict__ db,
                                                  float* __restrict__ out) {
  int r = blockIdx.x * 256 + threadIdx.x;
  float s = 0.f;
  #pragma unroll
  for (int i = 0; i < 16; ++i) s += part[(size_t)i * 32768 + r];
  float v = s + db[0];
  out[r * 3 + 0] = v;
  out[r * 3 + 1] = v;
  out[r * 3 + 2] = v;
}

// ---------------- launch ----------------

extern "C" void kernel_launch(void* const* d_in, const int* in_sizes, int n_in,
                              void* d_out, int out_size, void* d_ws, size_t ws_size,
                              hipStream_t stream) {
  const float* x      = (const float*)d_in[0];
  const float* enc_w1 = (const float*)d_in[1];
  const float* enc_b1 = (const float*)d_in[2];
  const float* enc_w2 = (const float*)d_in[3];
  const float* enc_b2 = (const float*)d_in[4];
  const float* initn  = (const float*)d_in[5];
  const float* g1w1   = (const float*)d_in[6];
  const float* g1b1   = (const float*)d_in[7];
  const float* g1w2   = (const float*)d_in[8];
  const float* g1b2   = (const float*)d_in[9];
  const float* g2w1   = (const float*)d_in[10];
  const float* g2b1   = (const float*)d_in[11];
  const float* g2w2   = (const float*)d_in[12];
  const float* g2b2   = (const float*)d_in[13];
  const float* dec_w  = (const float*)d_in[14];
  const float* dec_b  = (const float*)d_in[15];
  float* out = (float*)d_out;

  char* ws = (char*)d_ws;
  ushort_t* xb    = (ushort_t*)(ws + 0);          // 32768*512*2  = 33,554,432
  ushort_t* wtE1  = (ushort_t*)(ws + 33554432);   // 1024*512*2   =  1,048,576
  ushort_t* wtE2  = (ushort_t*)(ws + 34603008);   // 1024*1024*2  =  2,097,152
  ushort_t* wtG11 = (ushort_t*)(ws + 36700160);
  ushort_t* wtG12 = (ushort_t*)(ws + 38797312);
  ushort_t* wtG21 = (ushort_t*)(ws + 40894464);
  ushort_t* wtG22 = (ushort_t*)(ws + 42991616);
  float*    sInit = (float*)   (ws + 45088768);   // 4 KB
  ushort_t* bufA  = (ushort_t*)(ws + 45092864);   // 32768*1024*2 = 67,108,864
  ushort_t* bufB  = (ushort_t*)(ws + 112201728);  // 67,108,864
  float*    part  = (float*)   (ws + 112201728);  // reuse bufB region: 2 MB

  // prep: x->bf16, suminit, all 6 weight transposes
  k_cvt4<<<2048, 256, 0, stream>>>(x, xb, 32768 * 512 / 4);
  k_suminit<<<4, 256, 0, stream>>>(initn, sInit);
  {
    dim3 g(32, 32, 6);
    k_prep_w<<<g, 256, 0, stream>>>(enc_w1, enc_w2, g1w1, g1w2, g2w1, g2w2,
                                    wtE1, wtE2, wtG11, wtG12, wtG21, wtG22);
  }

  // e1 = relu(x @ enc_w1 + b1)
  gemm_bt<512, 0><<<2048, 256, 0, stream>>>(xb, wtE1, enc_b1, nullptr, bufA, nullptr);
  // S1 = 3*relu(e1 @ enc_w2 + b2) + sum_init
  gemm_bt<1024, 1><<<2048, 256, 0, stream>>>(bufA, wtE2, enc_b2, sInit, bufB, nullptr);
  // t1 = relu(S1 @ g1w1 + g1b1)
  gemm_bt<1024, 0><<<2048, 256, 0, stream>>>(bufB, wtG11, g1b1, nullptr, bufA, nullptr);
  // m2 = 3*relu(t1 @ g1w2 + g1b2)
  gemm_bt<1024, 2><<<2048, 256, 0, stream>>>(bufA, wtG12, g1b2, nullptr, bufB, nullptr);
  // t2 = relu(m2 @ g2w1 + g2b1)
  gemm_bt<1024, 0><<<2048, 256, 0, stream>>>(bufB, wtG21, g2b1, nullptr, bufA, nullptr);
  // fused GEMM6 + decoder partials: part[slot][row] = sum_col relu(t2@g2w2+b)*dec_w
  gemm_bt<1024, 3><<<2048, 256, 0, stream>>>(bufA, wtG22, g2b2, dec_w, nullptr, part);
  // final reduce + broadcast to 3 node columns
  k_decfinal<<<128, 256, 0, stream>>>(part, dec_b, out);
}

// Round 7
// 375.295 us; speedup vs baseline: 1.6176x; 1.6176x over previous
//
#include <hip/hip_runtime.h>
#include <stdint.h>

#define AS1 __attribute__((address_space(1)))
#define AS3 __attribute__((address_space(3)))

typedef unsigned short ushort_t;
typedef __attribute__((ext_vector_type(8))) short bf16x8;
typedef __attribute__((ext_vector_type(4))) float f32x4;

__device__ __forceinline__ ushort_t f2bf(float f) {
  union { float f; uint32_t u; } c; c.f = f;
  uint32_t u = c.u;
  return (ushort_t)((u + 0x7fffu + ((u >> 16) & 1u)) >> 16);  // RNE
}

// ---------------- prep kernels ----------------

__global__ __launch_bounds__(256) void k_cvt4(const float* __restrict__ in,
                                              ushort_t* __restrict__ out, int n4) {
  int i = blockIdx.x * blockDim.x + threadIdx.x;
  int stride = gridDim.x * blockDim.x;
  for (; i < n4; i += stride) {
    float4 v = ((const float4*)in)[i];
    ushort4 o;
    o.x = f2bf(v.x); o.y = f2bf(v.y); o.z = f2bf(v.z); o.w = f2bf(v.w);
    ((ushort4*)out)[i] = o;
  }
}

__global__ __launch_bounds__(256) void k_suminit(const float* __restrict__ init,
                                                 float* __restrict__ s) {
  int i = blockIdx.x * 256 + threadIdx.x;
  if (i < 1024) s[i] = init[i] + init[i + 1024] + init[i + 2048];
}

// all 6 weight transposes in one launch: W [K][N=1024] fp32 -> Wt [N][K] bf16
__global__ __launch_bounds__(256) void k_prep_w(
    const float* s0, const float* s1, const float* s2, const float* s3,
    const float* s4, const float* s5,
    ushort_t* d0, ushort_t* d1, ushort_t* d2, ushort_t* d3,
    ushort_t* d4, ushort_t* d5) {
  const float* S; ushort_t* D; int K = 1024;
  switch (blockIdx.z) {
    case 0: S = s0; D = d0; K = 512; break;
    case 1: S = s1; D = d1; break;
    case 2: S = s2; D = d2; break;
    case 3: S = s3; D = d3; break;
    case 4: S = s4; D = d4; break;
    default: S = s5; D = d5; break;
  }
  int k0 = blockIdx.y * 32;
  if (k0 >= K) return;
  __shared__ float tile[32][33];
  int tx = threadIdx.x & 31, ty = threadIdx.x >> 5;  // 32 x 8
  int n0 = blockIdx.x * 32;
  #pragma unroll
  for (int i = ty; i < 32; i += 8)
    tile[i][tx] = S[(size_t)(k0 + i) * 1024 + (n0 + tx)];
  __syncthreads();
  #pragma unroll
  for (int i = ty; i < 32; i += 8)
    D[(size_t)(n0 + i) * K + (k0 + tx)] = f2bf(tile[tx][i]);
}

// ---------------- GEMM: C[M,1024] = A[M,KT] * Bt[1024,KT]^T  (bf16 in, fp32 acc) ----------------
// EPI 0: C = bf16(relu(acc+bias))
// EPI 1: C = bf16(3*relu(acc+bias) + extra[col])
// EPI 2: C = bf16(3*relu(acc+bias))
// EPI 3: decoder fusion: part[slot][row] = sum_cols relu(acc+bias)*extra[col]  (no C write)

template <int KT, int EPI>
__global__ __launch_bounds__(256, 4)
void gemm_bt(const ushort_t* __restrict__ A, const ushort_t* __restrict__ Bt,
             const float* __restrict__ bias, const float* __restrict__ extra,
             ushort_t* __restrict__ C, float* __restrict__ part) {
  __shared__ char smem[32768];
  char* smA = smem;            // [128 rows][128 bytes] (BK=64 bf16), XOR-swizzled content
  char* smB = smem + 16384;    // same for Bt tile

  // XCD-aware swizzle: nwg = 2048, divisible by 8
  const int nwg = gridDim.x;
  const int cpx = nwg >> 3;
  int bid = blockIdx.x;
  int wg = (bid & 7) * cpx + (bid >> 3);
  const int mt = wg >> 3;  // 256 m-tiles
  const int nt = wg & 7;   // 8 n-tiles

  const int t = threadIdx.x;
  const int wave = t >> 6;
  const int lane = t & 63;
  const int wr = wave >> 1, wc = wave & 1;
  const int lrow = lane & 15;
  const int kq = lane >> 4;

  const char* Abase = (const char*)A + (size_t)mt * 128 * (KT * 2);
  const char* Bbase = (const char*)Bt + (size_t)nt * 128 * (KT * 2);

  // staging geometry: call i stages rows [i*32 .. i*32+31]; this thread's row:
  const int rbase = wave * 8 + (lane >> 3);
  // pre-swizzled global source column (16B units XORed with row&7)
  const int colOff = ((lane & 7) ^ (rbase & 7)) << 4;

  f32x4 acc[4][4];
  #pragma unroll
  for (int m = 0; m < 4; ++m)
    #pragma unroll
    for (int n = 0; n < 4; ++n)
      acc[m][n] = (f32x4){0.f, 0.f, 0.f, 0.f};

  constexpr int NKT = KT / 64;
  for (int kt = 0; kt < NKT; ++kt) {
    const size_t kb = (size_t)kt * 128;  // byte offset of K-tile in a row
    #pragma unroll
    for (int i = 0; i < 4; ++i) {
      int r = i * 32 + rbase;
      __builtin_amdgcn_global_load_lds(
          (const AS1 void*)(Abase + (size_t)r * (KT * 2) + kb + colOff),
          (AS3 void*)(smA + i * 4096 + wave * 1024), 16, 0, 0);
      __builtin_amdgcn_global_load_lds(
          (const AS1 void*)(Bbase + (size_t)r * (KT * 2) + kb + colOff),
          (AS3 void*)(smB + i * 4096 + wave * 1024), 16, 0, 0);
    }
    __syncthreads();
    #pragma unroll
    for (int ks = 0; ks < 2; ++ks) {
      bf16x8 af[4], bfv[4];
      #pragma unroll
      for (int m = 0; m < 4; ++m) {
        int r = wr * 64 + m * 16 + lrow;
        af[m] = *(const bf16x8*)(smA + r * 128 +
                                 ((ks * 64 + kq * 16) ^ ((r & 7) << 4)));
      }
      #pragma unroll
      for (int n = 0; n < 4; ++n) {
        int r = wc * 64 + n * 16 + lrow;
        bfv[n] = *(const bf16x8*)(smB + r * 128 +
                                  ((ks * 64 + kq * 16) ^ ((r & 7) << 4)));
      }
      #pragma unroll
      for (int m = 0; m < 4; ++m)
        #pragma unroll
        for (int n = 0; n < 4; ++n)
          acc[m][n] = __builtin_amdgcn_mfma_f32_16x16x32_bf16(af[m], bfv[n],
                                                              acc[m][n], 0, 0, 0);
    }
    __syncthreads();
  }

  // epilogue: C/D layout col = lane&15, row = (lane>>4)*4 + j
  const int row0 = mt * 128 + wr * 64;
  const int col0 = nt * 128 + wc * 64;
  if (EPI == 3) {
    float s[4][4];
    #pragma unroll
    for (int m = 0; m < 4; ++m)
      #pragma unroll
      for (int j = 0; j < 4; ++j) s[m][j] = 0.f;
    #pragma unroll
    for (int n = 0; n < 4; ++n) {
      int col = col0 + n * 16 + lrow;
      float bn = bias[col];
      float wn = extra[col];  // dec_w
      #pragma unroll
      for (int m = 0; m < 4; ++m)
        #pragma unroll
        for (int j = 0; j < 4; ++j) {
          float v = fmaxf(acc[m][n][j] + bn, 0.f);
          s[m][j] += v * wn;
        }
    }
    const int slot = nt * 2 + wc;
    #pragma unroll
    for (int m = 0; m < 4; ++m)
      #pragma unroll
      for (int j = 0; j < 4; ++j) {
        float v = s[m][j];
        v += __shfl_xor(v, 1);
        v += __shfl_xor(v, 2);
        v += __shfl_xor(v, 4);
        v += __shfl_xor(v, 8);
        if (lrow == 0)
          part[(size_t)slot * 32768 + (row0 + m * 16 + kq * 4 + j)] = v;
      }
  } else {
    float bn[4], en[4];
    #pragma unroll
    for (int n = 0; n < 4; ++n) {
      int col = col0 + n * 16 + lrow;
      bn[n] = bias[col];
      en[n] = (EPI == 1) ? extra[col] : 0.f;
    }
    // row-coherent store order: complete each 128B C line back-to-back
    #pragma unroll
    for (int m = 0; m < 4; ++m) {
      #pragma unroll
      for (int j = 0; j < 4; ++j) {
        int rb = row0 + m * 16 + kq * 4 + j;
        ushort_t* Crow = C + (size_t)rb * 1024 + col0 + lrow;
        #pragma unroll
        for (int n = 0; n < 4; ++n) {
          float v = acc[m][n][j] + bn[n];
          v = fmaxf(v, 0.f);
          if (EPI == 1) v = 3.f * v + en[n];
          else if (EPI == 2) v = 3.f * v;
          Crow[n * 16] = f2bf(v);
        }
      }
    }
  }
}

// ---------------- final decode reduce: out[r*3+{0,1,2}] = sum_s part[s][r] + dec_b ----------------

__global__ __launch_bounds__(256) void k_decfinal(const float* __restrict__ part,
                                                  const float* __restrict__ db,
                                                  float* __restrict__ out) {
  int r = blockIdx.x * 256 + threadIdx.x;
  float s = 0.f;
  #pragma unroll
  for (int i = 0; i < 16; ++i) s += part[(size_t)i * 32768 + r];
  float v = s + db[0];
  out[r * 3 + 0] = v;
  out[r * 3 + 1] = v;
  out[r * 3 + 2] = v;
}

// ---------------- launch ----------------

extern "C" void kernel_launch(void* const* d_in, const int* in_sizes, int n_in,
                              void* d_out, int out_size, void* d_ws, size_t ws_size,
                              hipStream_t stream) {
  const float* x      = (const float*)d_in[0];
  const float* enc_w1 = (const float*)d_in[1];
  const float* enc_b1 = (const float*)d_in[2];
  const float* enc_w2 = (const float*)d_in[3];
  const float* enc_b2 = (const float*)d_in[4];
  const float* initn  = (const float*)d_in[5];
  const float* g1w1   = (const float*)d_in[6];
  const float* g1b1   = (const float*)d_in[7];
  const float* g1w2   = (const float*)d_in[8];
  const float* g1b2   = (const float*)d_in[9];
  const float* g2w1   = (const float*)d_in[10];
  const float* g2b1   = (const float*)d_in[11];
  const float* g2w2   = (const float*)d_in[12];
  const float* g2b2   = (const float*)d_in[13];
  const float* dec_w  = (const float*)d_in[14];
  const float* dec_b  = (const float*)d_in[15];
  float* out = (float*)d_out;

  char* ws = (char*)d_ws;
  ushort_t* xb    = (ushort_t*)(ws + 0);          // 32768*512*2  = 33,554,432
  ushort_t* wtE1  = (ushort_t*)(ws + 33554432);   // 1024*512*2   =  1,048,576
  ushort_t* wtE2  = (ushort_t*)(ws + 34603008);   // 1024*1024*2  =  2,097,152
  ushort_t* wtG11 = (ushort_t*)(ws + 36700160);
  ushort_t* wtG12 = (ushort_t*)(ws + 38797312);
  ushort_t* wtG21 = (ushort_t*)(ws + 40894464);
  ushort_t* wtG22 = (ushort_t*)(ws + 42991616);
  float*    sInit = (float*)   (ws + 45088768);   // 4 KB
  ushort_t* bufA  = (ushort_t*)(ws + 45092864);   // 32768*1024*2 = 67,108,864
  ushort_t* bufB  = (ushort_t*)(ws + 112201728);  // 67,108,864
  float*    part  = (float*)   (ws + 112201728);  // reuse bufB region: 2 MB

  // prep: x->bf16, suminit, all 6 weight transposes
  k_cvt4<<<2048, 256, 0, stream>>>(x, xb, 32768 * 512 / 4);
  k_suminit<<<4, 256, 0, stream>>>(initn, sInit);
  {
    dim3 g(32, 32, 6);
    k_prep_w<<<g, 256, 0, stream>>>(enc_w1, enc_w2, g1w1, g1w2, g2w1, g2w2,
                                    wtE1, wtE2, wtG11, wtG12, wtG21, wtG22);
  }

  // e1 = relu(x @ enc_w1 + b1)
  gemm_bt<512, 0><<<2048, 256, 0, stream>>>(xb, wtE1, enc_b1, nullptr, bufA, nullptr);
  // S1 = 3*relu(e1 @ enc_w2 + b2) + sum_init
  gemm_bt<1024, 1><<<2048, 256, 0, stream>>>(bufA, wtE2, enc_b2, sInit, bufB, nullptr);
  // t1 = relu(S1 @ g1w1 + g1b1)
  gemm_bt<1024, 0><<<2048, 256, 0, stream>>>(bufB, wtG11, g1b1, nullptr, bufA, nullptr);
  // m2 = 3*relu(t1 @ g1w2 + g1b2)
  gemm_bt<1024, 2><<<2048, 256, 0, stream>>>(bufA, wtG12, g1b2, nullptr, bufB, nullptr);
  // t2 = relu(m2 @ g2w1 + g2b1)
  gemm_bt<1024, 0><<<2048, 256, 0, stream>>>(bufB, wtG21, g2b1, nullptr, bufA, nullptr);
  // fused GEMM6 + decoder partials: part[slot][row] = sum_col relu(t2@g2w2+b)*dec_w
  gemm_bt<1024, 3><<<2048, 256, 0, stream>>>(bufA, wtG22, g2b2, dec_w, nullptr, part);
  // final reduce + broadcast to 3 node columns
  k_decfinal<<<128, 256, 0, stream>>>(part, dec_b, out);
}